// Round 6
// baseline (1905.962 us; speedup 1.0000x reference)
//
#include <hip/hip_runtime.h>

#define N_ATOMS 100000
#define N_BONDS 200000
#define NEI 6
#define ITERS 6

#define MB_PAD 200064   // 1563*128 (also 3126*64)
#define MT_B 1563
#define MT_Q 3126       // fused_qattn grid: MB_PAD/64
#define MT_A 782
#define KL 320          // final K (287 padded to 320)
#define KVSTRIDE 768    // bytes per kv row: [K fp8 256 B | V bf16 512 B]
#define QSTR 260        // q LDS row stride (shorts); 260 -> conflict-free ds ops
#define AUX_NT 2        // CPol NT bit (gfx94x/950): evict-first, read-only safe

typedef __bf16 bf16x8 __attribute__((ext_vector_type(8)));
typedef float f32x4 __attribute__((ext_vector_type(4)));
typedef float f32x2 __attribute__((ext_vector_type(2)));

__device__ __forceinline__ float b2f(unsigned short u) {
  union { unsigned int i; float f; } x; x.i = ((unsigned int)u) << 16; return x.f;
}
__device__ __forceinline__ unsigned short f2b(float f) {
  union { float f; unsigned int i; } x; x.f = f;
  unsigned int r = (x.i + 0x7FFFu + ((x.i >> 16) & 1u)) >> 16;
  return (unsigned short)r;
}
__device__ __forceinline__ float lrelu(float v) { return v > 0.f ? v : 0.1f * v; }

// ---------------- fp8 e4m3fn encode/decode (HW builtins w/ SW fallback) ----
#if defined(__has_builtin)
#  if __has_builtin(__builtin_amdgcn_cvt_f32_fp8) && __has_builtin(__builtin_amdgcn_cvt_pk_fp8_f32)
#    define HW_FP8 1
#  endif
#  if __has_builtin(__builtin_amdgcn_cvt_pk_f32_fp8)
#    define HW_PKFP8 1
#  endif
#endif

__device__ __forceinline__ unsigned char f2e4m3_sw(float f) {
  union { float f; unsigned u; } x; x.f = f;
  unsigned s = (x.u >> 24) & 0x80u;
  unsigned ax = x.u & 0x7FFFFFFFu;
  if (ax >= 0x43E00000u) return (unsigned char)(s | 0x7Eu);  // clamp 448
  if (ax < 0x3A800000u)  return (unsigned char)s;            // < 2^-10 -> 0
  if (ax < 0x3C800000u) {                                    // subnormal: round(a*512)
    union { unsigned u; float f; } a; a.u = ax;
    unsigned n = (unsigned)(a.f * 512.0f + 0.5f);            // 1..8 (8 = min normal)
    return (unsigned char)(s | n);
  }
  unsigned r = ax + 0x0007FFFFu + ((ax >> 20) & 1u);         // RTNE to 3 mant bits
  unsigned e32 = r >> 23;
  unsigned mant = (r >> 20) & 7u;
  int e8 = (int)e32 - 120;
  if (e8 >= 16) return (unsigned char)(s | 0x7Eu);
  return (unsigned char)(s | ((unsigned)e8 << 3) | mant);
}
__device__ __forceinline__ float dec8_sw(unsigned b) {
  unsigned s = (b & 0x80u) << 24;
  unsigned e = (b >> 3) & 0xFu, m = b & 7u;
  if (e) { union { unsigned u; float f; } x; x.u = s | ((e + 120u) << 23) | (m << 20); return x.f; }
  float v = (float)m * 0.001953125f;
  return (b & 0x80u) ? -v : v;
}
#ifdef HW_FP8
__device__ __forceinline__ unsigned char f2e4m3(float f) {
  return (unsigned char)(__builtin_amdgcn_cvt_pk_fp8_f32(f, f, 0, false) & 0xFF);
}
#define DEC0(x) __builtin_amdgcn_cvt_f32_fp8((int)(x), 0)
#define DEC1(x) __builtin_amdgcn_cvt_f32_fp8((int)(x), 1)
#define DEC2(x) __builtin_amdgcn_cvt_f32_fp8((int)(x), 2)
#define DEC3(x) __builtin_amdgcn_cvt_f32_fp8((int)(x), 3)
#else
__device__ __forceinline__ unsigned char f2e4m3(float f) { return f2e4m3_sw(f); }
#define DEC0(x) dec8_sw((x) & 0xFFu)
#define DEC1(x) dec8_sw(((x) >> 8) & 0xFFu)
#define DEC2(x) dec8_sw(((x) >> 16) & 0xFFu)
#define DEC3(x) dec8_sw(((x) >> 24) & 0xFFu)
#endif

// B-side LDS XOR-swizzle (G4/T2): weights are stored pre-swizzled so the
// linear global_load_lds staging lands them swizzled in LDS; the bfv
// fragment read applies the same XOR -> 16-way conflict becomes <=2-way.
// k' = (k & ~63) | ((k & 63) ^ ((n & 7) << 3))   (shorts, per 128-B chunk)
__device__ __forceinline__ int kswz(int k, int n) {
  return (k & ~63) | ((k & 63) ^ ((n & 7) << 3));
}

// ---------------------------------------------------------------------------
// Weight pack: float32 in -> bf16 B^T copies (row-major [N,K]), PRE-SWIZZLED.
// wkvT [512][256]: n<256 -> Wk col n; else Wv col n-256  (fused KV GEMM)
// wqT [256][256]; wmsgT [256][128] (k<64: Wout, 64..100: Wemb, pad 0)
// wlastT [256][320] (k<256: W_last[31+k], 256..286: W_last[k-256], pad 0)
// ---------------------------------------------------------------------------
__global__ __launch_bounds__(256) void pack_weights(
    const float* __restrict__ Wq, const float* __restrict__ Wk,
    const float* __restrict__ Wv, const float* __restrict__ Wemb,
    const float* __restrict__ Wout, const float* __restrict__ Wlast,
    unsigned short* __restrict__ wkvT, unsigned short* __restrict__ wqT,
    unsigned short* __restrict__ wmsgT, unsigned short* __restrict__ wlastT)
{
  int t = blockIdx.x * 256 + threadIdx.x;   // grid = 512 blocks -> t < 131072
  {
    int n = t >> 8, k = t & 255;
    wkvT[n * 256 + kswz(k, n)] =
        f2b((n < 256) ? Wk[k * 256 + n] : Wv[k * 256 + (n - 256)]);
  }
  if (t < 65536) {
    int n = t >> 8, k = t & 255;
    wqT[n * 256 + kswz(k, n)] = f2b(Wq[k * 256 + n]);
  }
  if (t < 32768) {
    int n = t >> 7, k = t & 127;
    float v = 0.f;
    if (k < 64)       v = Wout[k * 256 + n];
    else if (k < 101) v = Wemb[(k - 64) * 256 + n];
    wmsgT[n * 128 + kswz(k, n)] = f2b(v);
  }
  if (t < 256 * KL) {
    int n = t / KL, k = t % KL;
    float v = 0.f;
    if (k < 256)      v = Wlast[(31 + k) * 256 + n];
    else if (k < 287) v = Wlast[(k - 256) * 256 + n];
    wlastT[n * KL + kswz(k, n)] = f2b(v);
  }
}

// A2 [MB_PAD][128]: cols 0..63 = 0 (att slot), 64..100 = bf16(fbonds), rest 0
__global__ __launch_bounds__(256) void pack_bonds(
    const float* __restrict__ fbonds, unsigned short* __restrict__ A2)
{
  int t = blockIdx.x * 256 + threadIdx.x;
  int r = t >> 7, c = t & 127;
  float v = 0.f;
  if (c >= 64 && c < 101 && r < N_BONDS) v = fbonds[r * 37 + (c - 64)];
  A2[t] = f2b(v);
}

// ---------------------------------------------------------------------------
// m97-style 128x128 bf16 GEMM. A [*,K] row-major bf16 (linear),
// BT [N,K] row-major bf16 PRE-SWIZZLED (see kswz).
// GRID IS TRANSPOSED (round 6): blockIdx.x = N-tile, blockIdx.y = M-tile.
// Consecutive blocks share the same A row-panel -> its 2-4 re-reads are
// temporally adjacent (L2/L3 hits) instead of full-array HBM re-passes
// (round 5 measured ~2.5x kv re-fetch from the resulting L3 thrash).
// EP: 1 +bias Xf[col] leaky -> bf16;
//     3 +bias Xf[col] leaky, row<Mreal guard -> FLOAT out
//     4 kv epilogue: col<256 -> fp8 @ row*768+col; else bf16 @ row*768+256+(col-256)*2
// ---------------------------------------------------------------------------
template<int EP>
__global__ __launch_bounds__(256) void gemm_bt(
    const unsigned short* __restrict__ A,
    const unsigned short* __restrict__ BT,
    unsigned short* __restrict__ C0,
    float* __restrict__ Fout,
    const float* __restrict__ Xf,
    int K, int N, int Mreal)
{
  __shared__ __align__(16) unsigned short As[128 * 64];
  __shared__ __align__(16) unsigned short Bs[128 * 64];
  const int tid  = threadIdx.x;
  const int wave = tid >> 6, lane = tid & 63;
  const int wr = wave >> 1, wc = wave & 1;
  const int lhi = lane >> 4, llo = lane & 15;
  const int mBase = blockIdx.y * 128;   // transposed grid
  const int nBase = blockIdx.x * 128;
  const int crow = tid >> 3, ccol = tid & 7;   // per-lane staging coords

  f32x4 acc[4][4];
  #pragma unroll
  for (int i = 0; i < 4; ++i)
    #pragma unroll
    for (int j = 0; j < 4; ++j)
      acc[i][j] = f32x4{0.f, 0.f, 0.f, 0.f};

  for (int k0 = 0; k0 < K; k0 += 64) {
    __syncthreads();
    #pragma unroll
    for (int r = 0; r < 4; ++r) {
      const unsigned short* ga =
          A + (size_t)(mBase + r * 32 + crow) * K + (k0 + ccol * 8);
      __builtin_amdgcn_global_load_lds(
          (const __attribute__((address_space(1))) void*)ga,
          (__attribute__((address_space(3))) void*)(As + r * 2048 + wave * 512), 16, 0, 0);
      const unsigned short* gb =
          BT + (size_t)(nBase + r * 32 + crow) * K + (k0 + ccol * 8);
      __builtin_amdgcn_global_load_lds(
          (const __attribute__((address_space(1))) void*)gb,
          (__attribute__((address_space(3))) void*)(Bs + r * 2048 + wave * 512), 16, 0, 0);
    }
    __syncthreads();
    #pragma unroll
    for (int ks = 0; ks < 2; ++ks) {
      bf16x8 af[4], bfv[4];
      #pragma unroll
      for (int i = 0; i < 4; ++i)
        af[i] = *reinterpret_cast<const bf16x8*>(&As[(wr * 64 + i * 16 + llo) * 64 + ks * 32 + lhi * 8]);
      #pragma unroll
      for (int j = 0; j < 4; ++j)
        bfv[j] = *reinterpret_cast<const bf16x8*>(
            &Bs[(wc * 64 + j * 16 + llo) * 64 + ((ks * 32 + lhi * 8) ^ ((llo & 7) << 3))]);
      #pragma unroll
      for (int i = 0; i < 4; ++i)
        #pragma unroll
        for (int j = 0; j < 4; ++j)
          acc[i][j] = __builtin_amdgcn_mfma_f32_16x16x32_bf16(af[i], bfv[j], acc[i][j], 0, 0, 0);
    }
  }

  #pragma unroll
  for (int i = 0; i < 4; ++i) {
    #pragma unroll
    for (int j = 0; j < 4; ++j) {
      const int col = nBase + wc * 64 + j * 16 + llo;
      #pragma unroll
      for (int r = 0; r < 4; ++r) {
        const int row = mBase + wr * 64 + i * 16 + lhi * 4 + r;
        const float v = acc[i][j][r];
        if (EP == 0) {
          C0[(size_t)row * N + col] = f2b(v);
        } else if (EP == 1) {
          C0[(size_t)row * N + col] = f2b(lrelu(v + Xf[col]));
        } else if (EP == 3) {
          if (row < Mreal) Fout[(size_t)row * N + col] = lrelu(v + Xf[col]);
        } else {  // EP == 4: mixed fp8-K / bf16-V strided kv row
          unsigned char* kvb = (unsigned char*)C0;
          if (nBase < 256) {
            kvb[(size_t)row * KVSTRIDE + col] = f2e4m3(v);
          } else {
            *(unsigned short*)(kvb + (size_t)row * KVSTRIDE + 256 +
                               (size_t)(col - 256) * 2) = f2b(v);
          }
        }
      }
    }
  }
}

// ---------------------------------------------------------------------------
// Fused q-GEMM + attention. One block = 64 bonds, 512 thr:
//   phase 1: q[64][256] = msg_tile @ WqT via MFMA (2x4 wave grid, 32x64/wave),
//            result kept in LDS (never touches HBM). msg staging uses the NT
//            cache hint: attn is the LAST reader of this msg generation and
//            each line is read exactly once -> keep this 102 MB stream from
//            evicting the 154 MB kv table (6x reuse) out of L3.
//   phase 2: 8 waves x 8 bonds, one bond at a time. Scalarized gather
//            addressing (readfirstlane -> SGPR base + lane offset),
//            packed fp8 decode.
// SCRATCH LESSON (rounds 3/4): per-bond arrays MUST be declared inside the
// loop body; conditional writes to outer-scope arrays defeat SROA -> scratch.
// ---------------------------------------------------------------------------
#ifdef HW_PKFP8
#define QKDOT(p_, kd_) do {                                                    \
    const f32x2 lo_ = __builtin_amdgcn_cvt_pk_f32_fp8((int)(kd_), false);      \
    const f32x2 hi_ = __builtin_amdgcn_cvt_pk_f32_fp8((int)(kd_), true);       \
    p_ = q0 * lo_.x + q1 * lo_.y + q2 * hi_.x + q3 * hi_.y;                    \
  } while (0)
#else
#define QKDOT(p_, kd_) do {                                                    \
    p_ = q0 * DEC0(kd_) + q1 * DEC1(kd_) + q2 * DEC2(kd_) + q3 * DEC3(kd_);    \
  } while (0)
#endif

__global__ __launch_bounds__(512, 6) void fused_qattn(
    const unsigned short* __restrict__ msg,
    const unsigned short* __restrict__ wqT,
    const unsigned char* __restrict__ kv,
    const int* __restrict__ bgraph,
    unsigned short* __restrict__ A2)
{
  // phase 1: As [64][64] @0 (4096 sh), Bs [256][64] @4096 (16384 sh)
  // phase 2: q [64][QSTR] @0 (16640 sh).  union = 20480 shorts = 40 KB
  __shared__ __align__(16) unsigned short smem[20480];
  const int tid  = threadIdx.x;
  const int wave = tid >> 6, lane = tid & 63;
  const int wr = wave >> 2, wc = wave & 3;     // 2x4 wave grid, 32x64 per wave
  const int lhi = lane >> 4, llo = lane & 15;
  const int mBase = blockIdx.x * 64;
  const int crow = tid >> 3, ccol = tid & 7;   // staging coords (512 thr)

  // ---- phase 1: q = msg_tile @ WqT (K=256, N=256) ----
  f32x4 acc[2][4];
  #pragma unroll
  for (int i = 0; i < 2; ++i)
    #pragma unroll
    for (int j = 0; j < 4; ++j)
      acc[i][j] = f32x4{0.f, 0.f, 0.f, 0.f};

  for (int k0 = 0; k0 < 256; k0 += 64) {
    __syncthreads();
    {  // A: 64 rows in one round (512 lanes x 16 B = 8 KB), NT policy
      const unsigned short* ga =
          msg + (size_t)(mBase + crow) * 256 + (k0 + ccol * 8);
      __builtin_amdgcn_global_load_lds(
          (const __attribute__((address_space(1))) void*)ga,
          (__attribute__((address_space(3))) void*)(smem + wave * 512), 16, 0, AUX_NT);
    }
    #pragma unroll
    for (int r = 0; r < 4; ++r) {            // B^T: 256 rows, 4 rounds (cached)
      const unsigned short* gb =
          wqT + (size_t)(r * 64 + crow) * 256 + (k0 + ccol * 8);
      __builtin_amdgcn_global_load_lds(
          (const __attribute__((address_space(1))) void*)gb,
          (__attribute__((address_space(3))) void*)(smem + 4096 + r * 4096 + wave * 512),
          16, 0, 0);
    }
    __syncthreads();
    #pragma unroll
    for (int ks = 0; ks < 2; ++ks) {
      bf16x8 af[2], bfv[4];
      #pragma unroll
      for (int i = 0; i < 2; ++i)
        af[i] = *reinterpret_cast<const bf16x8*>(
            &smem[(wr * 32 + i * 16 + llo) * 64 + ks * 32 + lhi * 8]);
      #pragma unroll
      for (int j = 0; j < 4; ++j)
        bfv[j] = *reinterpret_cast<const bf16x8*>(
            &smem[4096 + (wc * 64 + j * 16 + llo) * 64 +
                  ((ks * 32 + lhi * 8) ^ ((llo & 7) << 3))]);
      #pragma unroll
      for (int i = 0; i < 2; ++i)
        #pragma unroll
        for (int j = 0; j < 4; ++j)
          acc[i][j] = __builtin_amdgcn_mfma_f32_16x16x32_bf16(af[i], bfv[j], acc[i][j], 0, 0, 0);
    }
  }
  __syncthreads();   // all waves done reading As/Bs before overwrite with q

  #pragma unroll
  for (int i = 0; i < 2; ++i) {
    #pragma unroll
    for (int j = 0; j < 4; ++j) {
      const int col = wc * 64 + j * 16 + llo;
      #pragma unroll
      for (int r = 0; r < 4; ++r) {
        const int row = wr * 32 + i * 16 + lhi * 4 + r;
        smem[row * QSTR + col] = f2b(acc[i][j][r]);
      }
    }
  }
  __syncthreads();

  // ---- phase 2: attention, 8 bonds per wave (arrays scoped per-bond) ----
  const float SCL = 0.125f * 1.44269504089f;   // (1/sqrt(KD)) * log2(e)
  const int b0 = wave * 8;
  #pragma unroll 1
  for (int t2 = 0; t2 < 8; ++t2) {
    const int bl = b0 + t2;            // local bond 0..63
    const int wid = mBase + bl;
    if (wid >= N_BONDS) break;         // wave-uniform

    const int uw = __builtin_amdgcn_readfirstlane(wid);
    int bn[NEI];
    #pragma unroll
    for (int n = 0; n < NEI; ++n)
      bn[n] = __builtin_amdgcn_readfirstlane(bgraph[(size_t)uw * NEI + n]);
    unsigned kdw[NEI]; ushort4 vu[NEI];
    #pragma unroll
    for (int n = 0; n < NEI; ++n) {
      const unsigned char* bp = kv + (size_t)(unsigned)bn[n] * KVSTRIDE;
      kdw[n] = *reinterpret_cast<const unsigned*>(bp + lane * 4);
      vu[n]  = *reinterpret_cast<const ushort4*>(bp + 256 + lane * 8);
    }
    const ushort4 qu = *reinterpret_cast<const ushort4*>(&smem[bl * QSTR + lane * 4]);
    const float q0 = b2f(qu.x), q1 = b2f(qu.y), q2 = b2f(qu.z), q3 = b2f(qu.w);

    float sc[NEI];
    #pragma unroll
    for (int n = 0; n < NEI; ++n) {
      float p;
      QKDOT(p, kdw[n]);
      p += __shfl_xor(p, 1); p += __shfl_xor(p, 2);
      p += __shfl_xor(p, 4); p += __shfl_xor(p, 8);   // sum over 16-lane head group
      sc[n] = p * SCL + (bn[n] != 0 ? 0.f : -1e7f);
    }
    const float m =
        fmaxf(fmaxf(fmaxf(sc[0], sc[1]), fmaxf(sc[2], sc[3])), fmaxf(sc[4], sc[5]));
    float s = 0.f, o0 = 0.f, o1 = 0.f, o2 = 0.f, o3 = 0.f;
    #pragma unroll
    for (int n = 0; n < NEI; ++n) {
      const float e = exp2f(sc[n] - m);
      s += e;
      o0 += e * b2f(vu[n].x); o1 += e * b2f(vu[n].y);
      o2 += e * b2f(vu[n].z); o3 += e * b2f(vu[n].w);
    }
    const float inv = 0.25f * __builtin_amdgcn_rcpf(s);
    o0 *= inv; o1 *= inv; o2 *= inv; o3 *= inv;
    o0 += __shfl_xor(o0, 16); o0 += __shfl_xor(o0, 32);
    o1 += __shfl_xor(o1, 16); o1 += __shfl_xor(o1, 32);
    o2 += __shfl_xor(o2, 16); o2 += __shfl_xor(o2, 32);
    o3 += __shfl_xor(o3, 16); o3 += __shfl_xor(o3, 32);
    if (lane < 16) {
      ushort4 ov;
      ov.x = f2b(o0); ov.y = f2b(o1); ov.z = f2b(o2); ov.w = f2b(o3);
      *reinterpret_cast<ushort4*>(A2 + (size_t)wid * 128 + lane * 4) = ov;
    }
  }
}

// One wave per atom: nei_sum (fp32 accum) -> apad [MA_PAD][320]
// = [nei_sum(256) | bf16(fatoms)(31) | zeros]
__global__ __launch_bounds__(256) void atom_gather(
    const unsigned short* __restrict__ msg,
    const int* __restrict__ agraph,
    const float* __restrict__ fatoms,
    unsigned short* __restrict__ apad)
{
  const int aid  = blockIdx.x * 4 + (threadIdx.x >> 6);
  const int lane = threadIdx.x & 63;
  if (aid >= N_ATOMS) return;
  float s0 = 0, s1 = 0, s2 = 0, s3 = 0;
  #pragma unroll
  for (int n = 0; n < NEI; ++n) {
    const int b = agraph[aid * NEI + n];
    const ushort4 u = *reinterpret_cast<const ushort4*>(msg + (size_t)b * 256 + lane * 4);
    s0 += b2f(u.x); s1 += b2f(u.y); s2 += b2f(u.z); s3 += b2f(u.w);
  }
  ushort4 ov; ov.x = f2b(s0); ov.y = f2b(s1); ov.z = f2b(s2); ov.w = f2b(s3);
  *reinterpret_cast<ushort4*>(apad + (size_t)aid * KL + lane * 4) = ov;
  apad[(size_t)aid * KL + 256 + lane] =
      (lane < 31) ? f2b(fatoms[(size_t)aid * 31 + lane]) : (unsigned short)0;
}

// Diagnostic: zero output, out[0] = code (distinguishable absmax)
__global__ __launch_bounds__(256) void diag_out(float* out, int n, float code) {
  int t = blockIdx.x * 256 + threadIdx.x;
  if (t < n) out[t] = (t == 0) ? code : 0.f;
}

extern "C" void kernel_launch(void* const* d_in, const int* in_sizes, int n_in,
                              void* d_out, int out_size, void* d_ws, size_t ws_size,
                              hipStream_t stream) {
  const float* fatoms = (const float*)d_in[0];
  const float* fbonds = (const float*)d_in[1];
  const int* agraph   = (const int*)d_in[2];
  const int* bgraph   = (const int*)d_in[3];
  // d_in[4] lig_scope: unused by the reference computation
  const float* Wemb   = (const float*)d_in[5];
  const float* bemb   = (const float*)d_in[6];
  const float* Wq     = (const float*)d_in[7];
  const float* Wk     = (const float*)d_in[8];
  const float* Wv     = (const float*)d_in[9];
  const float* Wout   = (const float*)d_in[10];
  const float* Wlast  = (const float*)d_in[11];
  const float* blast  = (const float*)d_in[12];
  float* out          = (float*)d_out;

  char* ws = (char*)d_ws;
  size_t off = 0;
  auto alloc = [&](size_t bytes) {
    char* p = ws + off; off += (bytes + 511) & ~(size_t)511; return p;
  };
  unsigned short* msg    = (unsigned short*)alloc((size_t)MB_PAD * 256 * 2);
  unsigned char*  kv     = (unsigned char*)alloc((size_t)MB_PAD * KVSTRIDE); // atom-A alias
  unsigned short* A2     = (unsigned short*)alloc((size_t)MB_PAD * 128 * 2);
  unsigned short* wkvT   = (unsigned short*)alloc((size_t)512 * 256 * 2);
  unsigned short* wqT    = (unsigned short*)alloc((size_t)256 * 256 * 2);
  unsigned short* wmsgT  = (unsigned short*)alloc((size_t)256 * 128 * 2);
  unsigned short* wlastT = (unsigned short*)alloc((size_t)256 * KL * 2);
  unsigned short* apad   = (unsigned short*)kv;  // kv dead after loop (64.1 <= 153.6 MB)

  if (off > ws_size) {   // workspace too small: diagnostic
    diag_out<<<dim3((out_size + 255) / 256), dim3(256), 0, stream>>>(
        out, out_size, 10000.f + (float)(ws_size >> 20));
    return;
  }

  pack_weights<<<dim3(512), dim3(256), 0, stream>>>(
      Wq, Wk, Wv, Wemb, Wout, Wlast, wkvT, wqT, wmsgT, wlastT);
  pack_bonds<<<dim3(MB_PAD * 128 / 256), dim3(256), 0, stream>>>(fbonds, A2);

  // initial message: att cols of A2 are zero -> msg = leaky(fbonds@Wemb + b)
  // (grid transposed: x = N-tiles, y = M-tiles)
  gemm_bt<1><<<dim3(2, MT_B), dim3(256), 0, stream>>>(
      A2, wmsgT, msg, (float*)nullptr, bemb, 128, 256, MB_PAD);

  for (int it = 0; it < ITERS - 1; ++it) {
    // fused KV GEMM: [K-fp8 | V-bf16] strided rows (kv L3-hot for fused attn)
    gemm_bt<4><<<dim3(4, MT_B), dim3(256), 0, stream>>>(
        msg, wkvT, (unsigned short*)kv, (float*)nullptr, (const float*)nullptr,
        256, 512, MB_PAD);
    // q computed per-tile in LDS + attention; q never touches HBM
    fused_qattn<<<dim3(MT_Q), dim3(512), 0, stream>>>(msg, wqT, kv, bgraph, A2);
    // msg = leaky([att|fbonds] @ [Wout;Wemb] + b_emb)
    gemm_bt<1><<<dim3(2, MT_B), dim3(256), 0, stream>>>(
        A2, wmsgT, msg, (float*)nullptr, bemb, 128, 256, MB_PAD);
  }

  atom_gather<<<dim3(N_ATOMS / 4), dim3(256), 0, stream>>>(msg, agraph, fatoms, apad);
  gemm_bt<3><<<dim3(2, MT_A), dim3(256), 0, stream>>>(
      apad, wlastT, (unsigned short*)nullptr, out, blast, KL, 256, N_ATOMS);
}

// Round 7
// 1895.535 us; speedup vs baseline: 1.0055x; 1.0055x over previous
//
#include <hip/hip_runtime.h>

#define N_ATOMS 100000
#define N_BONDS 200000
#define NEI 6
#define ITERS 6

#define MB_PAD 200064   // 1563*128 (also 3126*64)
#define MT_B 1563
#define MT_Q 3126       // fused_qattn grid: MB_PAD/64
#define MT_A 782
#define KL 320          // final K (287 padded to 320)
#define KVSTRIDE 768    // bytes per kv row: [K fp8 256 B | V bf16 512 B]
#define QSTR 260        // q LDS row stride (shorts); 260 -> conflict-free ds ops
#define AUX_NT 2        // CPol NT bit: measured neutral (r6), kept (harmless)

typedef __bf16 bf16x8 __attribute__((ext_vector_type(8)));
typedef float f32x4 __attribute__((ext_vector_type(4)));
typedef float f32x2 __attribute__((ext_vector_type(2)));

__device__ __forceinline__ float b2f(unsigned short u) {
  union { unsigned int i; float f; } x; x.i = ((unsigned int)u) << 16; return x.f;
}
__device__ __forceinline__ unsigned short f2b(float f) {
  union { float f; unsigned int i; } x; x.f = f;
  unsigned int r = (x.i + 0x7FFFu + ((x.i >> 16) & 1u)) >> 16;
  return (unsigned short)r;
}
__device__ __forceinline__ float lrelu(float v) { return v > 0.f ? v : 0.1f * v; }

// ---------------- fp8 e4m3fn encode/decode (HW builtins w/ SW fallback) ----
#if defined(__has_builtin)
#  if __has_builtin(__builtin_amdgcn_cvt_f32_fp8) && __has_builtin(__builtin_amdgcn_cvt_pk_fp8_f32)
#    define HW_FP8 1
#  endif
#  if __has_builtin(__builtin_amdgcn_cvt_pk_f32_fp8)
#    define HW_PKFP8 1
#  endif
#endif

__device__ __forceinline__ unsigned char f2e4m3_sw(float f) {
  union { float f; unsigned u; } x; x.f = f;
  unsigned s = (x.u >> 24) & 0x80u;
  unsigned ax = x.u & 0x7FFFFFFFu;
  if (ax >= 0x43E00000u) return (unsigned char)(s | 0x7Eu);  // clamp 448
  if (ax < 0x3A800000u)  return (unsigned char)s;            // < 2^-10 -> 0
  if (ax < 0x3C800000u) {                                    // subnormal: round(a*512)
    union { unsigned u; float f; } a; a.u = ax;
    unsigned n = (unsigned)(a.f * 512.0f + 0.5f);            // 1..8 (8 = min normal)
    return (unsigned char)(s | n);
  }
  unsigned r = ax + 0x0007FFFFu + ((ax >> 20) & 1u);         // RTNE to 3 mant bits
  unsigned e32 = r >> 23;
  unsigned mant = (r >> 20) & 7u;
  int e8 = (int)e32 - 120;
  if (e8 >= 16) return (unsigned char)(s | 0x7Eu);
  return (unsigned char)(s | ((unsigned)e8 << 3) | mant);
}
__device__ __forceinline__ float dec8_sw(unsigned b) {
  unsigned s = (b & 0x80u) << 24;
  unsigned e = (b >> 3) & 0xFu, m = b & 7u;
  if (e) { union { unsigned u; float f; } x; x.u = s | ((e + 120u) << 23) | (m << 20); return x.f; }
  float v = (float)m * 0.001953125f;
  return (b & 0x80u) ? -v : v;
}
#ifdef HW_FP8
__device__ __forceinline__ unsigned char f2e4m3(float f) {
  return (unsigned char)(__builtin_amdgcn_cvt_pk_fp8_f32(f, f, 0, false) & 0xFF);
}
#define DEC0(x) __builtin_amdgcn_cvt_f32_fp8((int)(x), 0)
#define DEC1(x) __builtin_amdgcn_cvt_f32_fp8((int)(x), 1)
#define DEC2(x) __builtin_amdgcn_cvt_f32_fp8((int)(x), 2)
#define DEC3(x) __builtin_amdgcn_cvt_f32_fp8((int)(x), 3)
#else
__device__ __forceinline__ unsigned char f2e4m3(float f) { return f2e4m3_sw(f); }
#define DEC0(x) dec8_sw((x) & 0xFFu)
#define DEC1(x) dec8_sw(((x) >> 8) & 0xFFu)
#define DEC2(x) dec8_sw(((x) >> 16) & 0xFFu)
#define DEC3(x) dec8_sw(((x) >> 24) & 0xFFu)
#endif

// B-side LDS XOR-swizzle (G4/T2): weights are stored pre-swizzled so the
// linear global_load_lds staging lands them swizzled in LDS; the bfv
// fragment read applies the same XOR -> 16-way conflict becomes <=2-way.
// k' = (k & ~63) | ((k & 63) ^ ((n & 7) << 3))   (shorts, per 128-B chunk)
__device__ __forceinline__ int kswz(int k, int n) {
  return (k & ~63) | ((k & 63) ^ ((n & 7) << 3));
}

// ---------------------------------------------------------------------------
// Weight pack: float32 in -> bf16 B^T copies (row-major [N,K]), PRE-SWIZZLED.
// wkvT [512][256]: n<256 -> Wk col n; else Wv col n-256  (fused KV GEMM)
// wqT [256][256]; wmsgT [256][128] (k<64: Wout, 64..100: Wemb, pad 0)
// wlastT [256][320] (k<256: W_last[31+k], 256..286: W_last[k-256], pad 0)
// ---------------------------------------------------------------------------
__global__ __launch_bounds__(256) void pack_weights(
    const float* __restrict__ Wq, const float* __restrict__ Wk,
    const float* __restrict__ Wv, const float* __restrict__ Wemb,
    const float* __restrict__ Wout, const float* __restrict__ Wlast,
    unsigned short* __restrict__ wkvT, unsigned short* __restrict__ wqT,
    unsigned short* __restrict__ wmsgT, unsigned short* __restrict__ wlastT)
{
  int t = blockIdx.x * 256 + threadIdx.x;   // grid = 512 blocks -> t < 131072
  {
    int n = t >> 8, k = t & 255;
    wkvT[n * 256 + kswz(k, n)] =
        f2b((n < 256) ? Wk[k * 256 + n] : Wv[k * 256 + (n - 256)]);
  }
  if (t < 65536) {
    int n = t >> 8, k = t & 255;
    wqT[n * 256 + kswz(k, n)] = f2b(Wq[k * 256 + n]);
  }
  if (t < 32768) {
    int n = t >> 7, k = t & 127;
    float v = 0.f;
    if (k < 64)       v = Wout[k * 256 + n];
    else if (k < 101) v = Wemb[(k - 64) * 256 + n];
    wmsgT[n * 128 + kswz(k, n)] = f2b(v);
  }
  if (t < 256 * KL) {
    int n = t / KL, k = t % KL;
    float v = 0.f;
    if (k < 256)      v = Wlast[(31 + k) * 256 + n];
    else if (k < 287) v = Wlast[(k - 256) * 256 + n];
    wlastT[n * KL + kswz(k, n)] = f2b(v);
  }
}

// A2 [MB_PAD][128]: cols 0..63 = 0 (att slot), 64..100 = bf16(fbonds), rest 0
__global__ __launch_bounds__(256) void pack_bonds(
    const float* __restrict__ fbonds, unsigned short* __restrict__ A2)
{
  int t = blockIdx.x * 256 + threadIdx.x;
  int r = t >> 7, c = t & 127;
  float v = 0.f;
  if (c >= 64 && c < 101 && r < N_BONDS) v = fbonds[r * 37 + (c - 64)];
  A2[t] = f2b(v);
}

// ---------------------------------------------------------------------------
// m97-style 128x128 bf16 GEMM. A [*,K] row-major bf16 (linear),
// BT [N,K] row-major bf16 PRE-SWIZZLED (see kswz).
// Grid transposed (r6): blockIdx.x = N-tile, blockIdx.y = M-tile (neutral
// measured, kept: A row-panel re-reads are temporally adjacent).
// EP: 1 +bias Xf[col] leaky -> bf16;
//     3 +bias Xf[col] leaky, row<Mreal guard -> FLOAT out
//     4 kv epilogue: col<256 -> fp8 @ row*768+col; else bf16 @ row*768+256+(col-256)*2
// ---------------------------------------------------------------------------
template<int EP>
__global__ __launch_bounds__(256) void gemm_bt(
    const unsigned short* __restrict__ A,
    const unsigned short* __restrict__ BT,
    unsigned short* __restrict__ C0,
    float* __restrict__ Fout,
    const float* __restrict__ Xf,
    int K, int N, int Mreal)
{
  __shared__ __align__(16) unsigned short As[128 * 64];
  __shared__ __align__(16) unsigned short Bs[128 * 64];
  const int tid  = threadIdx.x;
  const int wave = tid >> 6, lane = tid & 63;
  const int wr = wave >> 1, wc = wave & 1;
  const int lhi = lane >> 4, llo = lane & 15;
  const int mBase = blockIdx.y * 128;   // transposed grid
  const int nBase = blockIdx.x * 128;
  const int crow = tid >> 3, ccol = tid & 7;   // per-lane staging coords

  f32x4 acc[4][4];
  #pragma unroll
  for (int i = 0; i < 4; ++i)
    #pragma unroll
    for (int j = 0; j < 4; ++j)
      acc[i][j] = f32x4{0.f, 0.f, 0.f, 0.f};

  for (int k0 = 0; k0 < K; k0 += 64) {
    __syncthreads();
    #pragma unroll
    for (int r = 0; r < 4; ++r) {
      const unsigned short* ga =
          A + (size_t)(mBase + r * 32 + crow) * K + (k0 + ccol * 8);
      __builtin_amdgcn_global_load_lds(
          (const __attribute__((address_space(1))) void*)ga,
          (__attribute__((address_space(3))) void*)(As + r * 2048 + wave * 512), 16, 0, 0);
      const unsigned short* gb =
          BT + (size_t)(nBase + r * 32 + crow) * K + (k0 + ccol * 8);
      __builtin_amdgcn_global_load_lds(
          (const __attribute__((address_space(1))) void*)gb,
          (__attribute__((address_space(3))) void*)(Bs + r * 2048 + wave * 512), 16, 0, 0);
    }
    __syncthreads();
    #pragma unroll
    for (int ks = 0; ks < 2; ++ks) {
      bf16x8 af[4], bfv[4];
      #pragma unroll
      for (int i = 0; i < 4; ++i)
        af[i] = *reinterpret_cast<const bf16x8*>(&As[(wr * 64 + i * 16 + llo) * 64 + ks * 32 + lhi * 8]);
      #pragma unroll
      for (int j = 0; j < 4; ++j)
        bfv[j] = *reinterpret_cast<const bf16x8*>(
            &Bs[(wc * 64 + j * 16 + llo) * 64 + ((ks * 32 + lhi * 8) ^ ((llo & 7) << 3))]);
      #pragma unroll
      for (int i = 0; i < 4; ++i)
        #pragma unroll
        for (int j = 0; j < 4; ++j)
          acc[i][j] = __builtin_amdgcn_mfma_f32_16x16x32_bf16(af[i], bfv[j], acc[i][j], 0, 0, 0);
    }
  }

  #pragma unroll
  for (int i = 0; i < 4; ++i) {
    #pragma unroll
    for (int j = 0; j < 4; ++j) {
      const int col = nBase + wc * 64 + j * 16 + llo;
      #pragma unroll
      for (int r = 0; r < 4; ++r) {
        const int row = mBase + wr * 64 + i * 16 + lhi * 4 + r;
        const float v = acc[i][j][r];
        if (EP == 0) {
          C0[(size_t)row * N + col] = f2b(v);
        } else if (EP == 1) {
          C0[(size_t)row * N + col] = f2b(lrelu(v + Xf[col]));
        } else if (EP == 3) {
          if (row < Mreal) Fout[(size_t)row * N + col] = lrelu(v + Xf[col]);
        } else {  // EP == 4: mixed fp8-K / bf16-V strided kv row
          unsigned char* kvb = (unsigned char*)C0;
          if (nBase < 256) {
            kvb[(size_t)row * KVSTRIDE + col] = f2e4m3(v);
          } else {
            *(unsigned short*)(kvb + (size_t)row * KVSTRIDE + 256 +
                               (size_t)(col - 256) * 2) = f2b(v);
          }
        }
      }
    }
  }
}

// ---------------------------------------------------------------------------
// Fused q-GEMM + attention. One block = 64 bonds, 512 thr:
//   phase 1: q[64][256] = msg_tile @ WqT via MFMA, result kept in LDS.
//   phase 2: 8 waves x 8 bonds. N_BONDS = 3125*64 exactly -> every wave in
//     blocks 0..3124 has ALL 8 bonds valid; block 3125 has none. So the fast
//     path is a fully-unrolled straight-line sequence of 8 independent bond
//     bodies (no conditionals, all indices compile-time) -> SROA promotes
//     everything AND the scheduler hoists later bonds' gather loads above
//     earlier bonds' compute (2-3 12-load batches in flight = the MLP that
//     round 5's `#pragma unroll 1` serial loop lacked).
// SCRATCH LESSON (r3/r4): conditional writes to loop-carried arrays defeat
// SROA -> allocas -> scratch (WRITE_SIZE 25 -> 580-990 MB). This version has
// no conditionals in the fast path at all.
// ---------------------------------------------------------------------------
#ifdef HW_PKFP8
#define QKDOT(p_, kd_) do {                                                    \
    const f32x2 lo_ = __builtin_amdgcn_cvt_pk_f32_fp8((int)(kd_), false);      \
    const f32x2 hi_ = __builtin_amdgcn_cvt_pk_f32_fp8((int)(kd_), true);       \
    p_ = q0 * lo_.x + q1 * lo_.y + q2 * hi_.x + q3 * hi_.y;                    \
  } while (0)
#else
#define QKDOT(p_, kd_) do {                                                    \
    p_ = q0 * DEC0(kd_) + q1 * DEC1(kd_) + q2 * DEC2(kd_) + q3 * DEC3(kd_);    \
  } while (0)
#endif

// One full bond: gather (scalarized base addressing) + score + softmax + PV.
// Everything block-scoped -> registers only.
#define ATTN_BODY(BL) do {                                                     \
    const int bl_ = (BL);                                                      \
    const int uw_ = __builtin_amdgcn_readfirstlane(mBase + bl_);               \
    int bn_[NEI];                                                              \
    _Pragma("unroll")                                                          \
    for (int n = 0; n < NEI; ++n)                                              \
      bn_[n] = __builtin_amdgcn_readfirstlane(bgraph[(size_t)uw_ * NEI + n]);  \
    unsigned kd_[NEI]; ushort4 vu_[NEI];                                       \
    _Pragma("unroll")                                                          \
    for (int n = 0; n < NEI; ++n) {                                            \
      const unsigned char* bp_ = kv + (size_t)(unsigned)bn_[n] * KVSTRIDE;     \
      kd_[n] = *reinterpret_cast<const unsigned*>(bp_ + lane * 4);             \
      vu_[n] = *reinterpret_cast<const ushort4*>(bp_ + 256 + lane * 8);        \
    }                                                                          \
    const ushort4 qu_ = *reinterpret_cast<const ushort4*>(                     \
        &smem[bl_ * QSTR + lane * 4]);                                         \
    const float q0 = b2f(qu_.x), q1 = b2f(qu_.y);                              \
    const float q2 = b2f(qu_.z), q3 = b2f(qu_.w);                              \
    float sc_[NEI];                                                            \
    _Pragma("unroll")                                                          \
    for (int n = 0; n < NEI; ++n) {                                            \
      float p_;                                                                \
      QKDOT(p_, kd_[n]);                                                       \
      p_ += __shfl_xor(p_, 1); p_ += __shfl_xor(p_, 2);                        \
      p_ += __shfl_xor(p_, 4); p_ += __shfl_xor(p_, 8);                        \
      sc_[n] = p_ * SCL + (bn_[n] != 0 ? 0.f : -1e7f);                         \
    }                                                                          \
    const float m_ =                                                           \
        fmaxf(fmaxf(fmaxf(sc_[0], sc_[1]), fmaxf(sc_[2], sc_[3])),             \
              fmaxf(sc_[4], sc_[5]));                                          \
    float s_ = 0.f, o0_ = 0.f, o1_ = 0.f, o2_ = 0.f, o3_ = 0.f;                \
    _Pragma("unroll")                                                          \
    for (int n = 0; n < NEI; ++n) {                                            \
      const float e_ = exp2f(sc_[n] - m_);                                     \
      s_ += e_;                                                                \
      o0_ += e_ * b2f(vu_[n].x); o1_ += e_ * b2f(vu_[n].y);                    \
      o2_ += e_ * b2f(vu_[n].z); o3_ += e_ * b2f(vu_[n].w);                    \
    }                                                                          \
    const float inv_ = 0.25f * __builtin_amdgcn_rcpf(s_);                      \
    o0_ *= inv_; o1_ *= inv_; o2_ *= inv_; o3_ *= inv_;                        \
    o0_ += __shfl_xor(o0_, 16); o0_ += __shfl_xor(o0_, 32);                    \
    o1_ += __shfl_xor(o1_, 16); o1_ += __shfl_xor(o1_, 32);                    \
    o2_ += __shfl_xor(o2_, 16); o2_ += __shfl_xor(o2_, 32);                    \
    o3_ += __shfl_xor(o3_, 16); o3_ += __shfl_xor(o3_, 32);                    \
    if (lane < 16) {                                                           \
      ushort4 ov_;                                                             \
      ov_.x = f2b(o0_); ov_.y = f2b(o1_);                                      \
      ov_.z = f2b(o2_); ov_.w = f2b(o3_);                                      \
      *reinterpret_cast<ushort4*>(                                             \
          A2 + (size_t)(mBase + bl_) * 128 + lane * 4) = ov_;                  \
    }                                                                          \
  } while (0)

__global__ __launch_bounds__(512, 6) void fused_qattn(
    const unsigned short* __restrict__ msg,
    const unsigned short* __restrict__ wqT,
    const unsigned char* __restrict__ kv,
    const int* __restrict__ bgraph,
    unsigned short* __restrict__ A2)
{
  // phase 1: As [64][64] @0 (4096 sh), Bs [256][64] @4096 (16384 sh)
  // phase 2: q [64][QSTR] @0 (16640 sh).  union = 20480 shorts = 40 KB
  // (40 KB -> 4 blocks/CU = the 32-waves/CU ceiling; smaller LDS buys nothing)
  __shared__ __align__(16) unsigned short smem[20480];
  const int tid  = threadIdx.x;
  const int wave = tid >> 6, lane = tid & 63;
  const int wr = wave >> 2, wc = wave & 3;     // 2x4 wave grid, 32x64 per wave
  const int lhi = lane >> 4, llo = lane & 15;
  const int mBase = blockIdx.x * 64;
  const int crow = tid >> 3, ccol = tid & 7;   // staging coords (512 thr)

  // ---- phase 1: q = msg_tile @ WqT (K=256, N=256) ----
  f32x4 acc[2][4];
  #pragma unroll
  for (int i = 0; i < 2; ++i)
    #pragma unroll
    for (int j = 0; j < 4; ++j)
      acc[i][j] = f32x4{0.f, 0.f, 0.f, 0.f};

  for (int k0 = 0; k0 < 256; k0 += 64) {
    __syncthreads();
    {  // A: 64 rows in one round (512 lanes x 16 B = 8 KB), NT policy
      const unsigned short* ga =
          msg + (size_t)(mBase + crow) * 256 + (k0 + ccol * 8);
      __builtin_amdgcn_global_load_lds(
          (const __attribute__((address_space(1))) void*)ga,
          (__attribute__((address_space(3))) void*)(smem + wave * 512), 16, 0, AUX_NT);
    }
    #pragma unroll
    for (int r = 0; r < 4; ++r) {            // B^T: 256 rows, 4 rounds (cached)
      const unsigned short* gb =
          wqT + (size_t)(r * 64 + crow) * 256 + (k0 + ccol * 8);
      __builtin_amdgcn_global_load_lds(
          (const __attribute__((address_space(1))) void*)gb,
          (__attribute__((address_space(3))) void*)(smem + 4096 + r * 4096 + wave * 512),
          16, 0, 0);
    }
    __syncthreads();
    #pragma unroll
    for (int ks = 0; ks < 2; ++ks) {
      bf16x8 af[2], bfv[4];
      #pragma unroll
      for (int i = 0; i < 2; ++i)
        af[i] = *reinterpret_cast<const bf16x8*>(
            &smem[(wr * 32 + i * 16 + llo) * 64 + ks * 32 + lhi * 8]);
      #pragma unroll
      for (int j = 0; j < 4; ++j)
        bfv[j] = *reinterpret_cast<const bf16x8*>(
            &smem[4096 + (wc * 64 + j * 16 + llo) * 64 +
                  ((ks * 32 + lhi * 8) ^ ((llo & 7) << 3))]);
      #pragma unroll
      for (int i = 0; i < 2; ++i)
        #pragma unroll
        for (int j = 0; j < 4; ++j)
          acc[i][j] = __builtin_amdgcn_mfma_f32_16x16x32_bf16(af[i], bfv[j], acc[i][j], 0, 0, 0);
    }
  }
  __syncthreads();   // all waves done reading As/Bs before overwrite with q

  #pragma unroll
  for (int i = 0; i < 2; ++i) {
    #pragma unroll
    for (int j = 0; j < 4; ++j) {
      const int col = wc * 64 + j * 16 + llo;
      #pragma unroll
      for (int r = 0; r < 4; ++r) {
        const int row = wr * 32 + i * 16 + lhi * 4 + r;
        smem[row * QSTR + col] = f2b(acc[i][j][r]);
      }
    }
  }
  __syncthreads();

  // ---- phase 2: attention ----
  const float SCL = 0.125f * 1.44269504089f;   // (1/sqrt(KD)) * log2(e)
  const int b0 = wave * 8;
  const int nv = N_BONDS - (mBase + b0);
  if (nv >= 8) {
    // fast path: all 8 bonds valid (every wave in blocks 0..3124).
    // Straight-line, no conditionals -> compiler overlaps gathers across bonds.
    ATTN_BODY(b0 + 0);
    ATTN_BODY(b0 + 1);
    ATTN_BODY(b0 + 2);
    ATTN_BODY(b0 + 3);
    ATTN_BODY(b0 + 4);
    ATTN_BODY(b0 + 5);
    ATTN_BODY(b0 + 6);
    ATTN_BODY(b0 + 7);
  } else if (nv > 0) {
    // safety net (unreachable for N_BONDS = 3125*64, kept for robustness)
    #pragma unroll 1
    for (int t2 = 0; t2 < nv; ++t2) ATTN_BODY(b0 + t2);
  }
}

// One wave per atom: nei_sum (fp32 accum) -> apad [MA_PAD][320]
// = [nei_sum(256) | bf16(fatoms)(31) | zeros]
__global__ __launch_bounds__(256) void atom_gather(
    const unsigned short* __restrict__ msg,
    const int* __restrict__ agraph,
    const float* __restrict__ fatoms,
    unsigned short* __restrict__ apad)
{
  const int aid  = blockIdx.x * 4 + (threadIdx.x >> 6);
  const int lane = threadIdx.x & 63;
  if (aid >= N_ATOMS) return;
  float s0 = 0, s1 = 0, s2 = 0, s3 = 0;
  #pragma unroll
  for (int n = 0; n < NEI; ++n) {
    const int b = agraph[aid * NEI + n];
    const ushort4 u = *reinterpret_cast<const ushort4*>(msg + (size_t)b * 256 + lane * 4);
    s0 += b2f(u.x); s1 += b2f(u.y); s2 += b2f(u.z); s3 += b2f(u.w);
  }
  ushort4 ov; ov.x = f2b(s0); ov.y = f2b(s1); ov.z = f2b(s2); ov.w = f2b(s3);
  *reinterpret_cast<ushort4*>(apad + (size_t)aid * KL + lane * 4) = ov;
  apad[(size_t)aid * KL + 256 + lane] =
      (lane < 31) ? f2b(fatoms[(size_t)aid * 31 + lane]) : (unsigned short)0;
}

// Diagnostic: zero output, out[0] = code (distinguishable absmax)
__global__ __launch_bounds__(256) void diag_out(float* out, int n, float code) {
  int t = blockIdx.x * 256 + threadIdx.x;
  if (t < n) out[t] = (t == 0) ? code : 0.f;
}

extern "C" void kernel_launch(void* const* d_in, const int* in_sizes, int n_in,
                              void* d_out, int out_size, void* d_ws, size_t ws_size,
                              hipStream_t stream) {
  const float* fatoms = (const float*)d_in[0];
  const float* fbonds = (const float*)d_in[1];
  const int* agraph   = (const int*)d_in[2];
  const int* bgraph   = (const int*)d_in[3];
  // d_in[4] lig_scope: unused by the reference computation
  const float* Wemb   = (const float*)d_in[5];
  const float* bemb   = (const float*)d_in[6];
  const float* Wq     = (const float*)d_in[7];
  const float* Wk     = (const float*)d_in[8];
  const float* Wv     = (const float*)d_in[9];
  const float* Wout   = (const float*)d_in[10];
  const float* Wlast  = (const float*)d_in[11];
  const float* blast  = (const float*)d_in[12];
  float* out          = (float*)d_out;

  char* ws = (char*)d_ws;
  size_t off = 0;
  auto alloc = [&](size_t bytes) {
    char* p = ws + off; off += (bytes + 511) & ~(size_t)511; return p;
  };
  unsigned short* msg    = (unsigned short*)alloc((size_t)MB_PAD * 256 * 2);
  unsigned char*  kv     = (unsigned char*)alloc((size_t)MB_PAD * KVSTRIDE); // atom-A alias
  unsigned short* A2     = (unsigned short*)alloc((size_t)MB_PAD * 128 * 2);
  unsigned short* wkvT   = (unsigned short*)alloc((size_t)512 * 256 * 2);
  unsigned short* wqT    = (unsigned short*)alloc((size_t)256 * 256 * 2);
  unsigned short* wmsgT  = (unsigned short*)alloc((size_t)256 * 128 * 2);
  unsigned short* wlastT = (unsigned short*)alloc((size_t)256 * KL * 2);
  unsigned short* apad   = (unsigned short*)kv;  // kv dead after loop (64.1 <= 153.6 MB)

  if (off > ws_size) {   // workspace too small: diagnostic
    diag_out<<<dim3((out_size + 255) / 256), dim3(256), 0, stream>>>(
        out, out_size, 10000.f + (float)(ws_size >> 20));
    return;
  }

  pack_weights<<<dim3(512), dim3(256), 0, stream>>>(
      Wq, Wk, Wv, Wemb, Wout, Wlast, wkvT, wqT, wmsgT, wlastT);
  pack_bonds<<<dim3(MB_PAD * 128 / 256), dim3(256), 0, stream>>>(fbonds, A2);

  // initial message: att cols of A2 are zero -> msg = leaky(fbonds@Wemb + b)
  // (grid transposed: x = N-tiles, y = M-tiles)
  gemm_bt<1><<<dim3(2, MT_B), dim3(256), 0, stream>>>(
      A2, wmsgT, msg, (float*)nullptr, bemb, 128, 256, MB_PAD);

  for (int it = 0; it < ITERS - 1; ++it) {
    // fused KV GEMM: [K-fp8 | V-bf16] strided rows (kv L3-hot for fused attn)
    gemm_bt<4><<<dim3(4, MT_B), dim3(256), 0, stream>>>(
        msg, wkvT, (unsigned short*)kv, (float*)nullptr, (const float*)nullptr,
        256, 512, MB_PAD);
    // q computed per-tile in LDS + attention; q never touches HBM
    fused_qattn<<<dim3(MT_Q), dim3(512), 0, stream>>>(msg, wqT, kv, bgraph, A2);
    // msg = leaky([att|fbonds] @ [Wout;Wemb] + b_emb)
    gemm_bt<1><<<dim3(2, MT_B), dim3(256), 0, stream>>>(
        A2, wmsgT, msg, (float*)nullptr, bemb, 128, 256, MB_PAD);
  }

  atom_gather<<<dim3(N_ATOMS / 4), dim3(256), 0, stream>>>(msg, agraph, fatoms, apad);
  gemm_bt<3><<<dim3(2, MT_A), dim3(256), 0, stream>>>(
      apad, wlastT, (unsigned short*)nullptr, out, blast, KL, 256, N_ATOMS);
}

// Round 8
// 1855.892 us; speedup vs baseline: 1.0270x; 1.0214x over previous
//
#include <hip/hip_runtime.h>

#define N_ATOMS 100000
#define N_BONDS 200000
#define NEI 6
#define ITERS 6

#define MB_PAD 200064   // 1563*128 (also 3126*64)
#define MT_B 1563
#define MT_Q 3126       // fused_qattn grid: MB_PAD/64
#define MT_A 782
#define KL 320          // final K (287 padded to 320)
#define KVSTRIDE 768    // bytes per kv row: [K fp8 256 B | V bf16 512 B]
#define QSTR 260        // q LDS row stride (shorts); 260 -> conflict-free ds ops
#define AUX_NT 2        // CPol NT bit: measured neutral (r6), kept (harmless)

typedef __bf16 bf16x8 __attribute__((ext_vector_type(8)));
typedef float f32x4 __attribute__((ext_vector_type(4)));
typedef float f32x2 __attribute__((ext_vector_type(2)));

__device__ __forceinline__ float b2f(unsigned short u) {
  union { unsigned int i; float f; } x; x.i = ((unsigned int)u) << 16; return x.f;
}
__device__ __forceinline__ unsigned short f2b(float f) {
  union { float f; unsigned int i; } x; x.f = f;
  unsigned int r = (x.i + 0x7FFFu + ((x.i >> 16) & 1u)) >> 16;
  return (unsigned short)r;
}
__device__ __forceinline__ float lrelu(float v) { return v > 0.f ? v : 0.1f * v; }

// ---------------- fp8 e4m3fn encode/decode (HW builtins w/ SW fallback) ----
#if defined(__has_builtin)
#  if __has_builtin(__builtin_amdgcn_cvt_f32_fp8) && __has_builtin(__builtin_amdgcn_cvt_pk_fp8_f32)
#    define HW_FP8 1
#  endif
#  if __has_builtin(__builtin_amdgcn_cvt_pk_f32_fp8)
#    define HW_PKFP8 1
#  endif
#endif

__device__ __forceinline__ unsigned char f2e4m3_sw(float f) {
  union { float f; unsigned u; } x; x.f = f;
  unsigned s = (x.u >> 24) & 0x80u;
  unsigned ax = x.u & 0x7FFFFFFFu;
  if (ax >= 0x43E00000u) return (unsigned char)(s | 0x7Eu);  // clamp 448
  if (ax < 0x3A800000u)  return (unsigned char)s;            // < 2^-10 -> 0
  if (ax < 0x3C800000u) {                                    // subnormal: round(a*512)
    union { unsigned u; float f; } a; a.u = ax;
    unsigned n = (unsigned)(a.f * 512.0f + 0.5f);            // 1..8 (8 = min normal)
    return (unsigned char)(s | n);
  }
  unsigned r = ax + 0x0007FFFFu + ((ax >> 20) & 1u);         // RTNE to 3 mant bits
  unsigned e32 = r >> 23;
  unsigned mant = (r >> 20) & 7u;
  int e8 = (int)e32 - 120;
  if (e8 >= 16) return (unsigned char)(s | 0x7Eu);
  return (unsigned char)(s | ((unsigned)e8 << 3) | mant);
}
__device__ __forceinline__ float dec8_sw(unsigned b) {
  unsigned s = (b & 0x80u) << 24;
  unsigned e = (b >> 3) & 0xFu, m = b & 7u;
  if (e) { union { unsigned u; float f; } x; x.u = s | ((e + 120u) << 23) | (m << 20); return x.f; }
  float v = (float)m * 0.001953125f;
  return (b & 0x80u) ? -v : v;
}
#ifdef HW_FP8
__device__ __forceinline__ unsigned char f2e4m3(float f) {
  return (unsigned char)(__builtin_amdgcn_cvt_pk_fp8_f32(f, f, 0, false) & 0xFF);
}
#define DEC0(x) __builtin_amdgcn_cvt_f32_fp8((int)(x), 0)
#define DEC1(x) __builtin_amdgcn_cvt_f32_fp8((int)(x), 1)
#define DEC2(x) __builtin_amdgcn_cvt_f32_fp8((int)(x), 2)
#define DEC3(x) __builtin_amdgcn_cvt_f32_fp8((int)(x), 3)
#else
__device__ __forceinline__ unsigned char f2e4m3(float f) { return f2e4m3_sw(f); }
#define DEC0(x) dec8_sw((x) & 0xFFu)
#define DEC1(x) dec8_sw(((x) >> 8) & 0xFFu)
#define DEC2(x) dec8_sw(((x) >> 16) & 0xFFu)
#define DEC3(x) dec8_sw(((x) >> 24) & 0xFFu)
#endif

// B-side LDS XOR-swizzle (G4/T2): weights are stored pre-swizzled so the
// linear global_load_lds staging lands them swizzled in LDS; the bfv
// fragment read applies the same XOR -> 16-way conflict becomes <=2-way.
// k' = (k & ~63) | ((k & 63) ^ ((n & 7) << 3))   (shorts, per 128-B chunk)
__device__ __forceinline__ int kswz(int k, int n) {
  return (k & ~63) | ((k & 63) ^ ((n & 7) << 3));
}

// ---------------------------------------------------------------------------
// Weight pack: float32 in -> bf16 B^T copies (row-major [N,K]), PRE-SWIZZLED.
// wkvT [512][256]: n<256 -> Wk col n; else Wv col n-256  (fused KV GEMM)
// wqT [256][256]; wmsgT [256][128] (k<64: Wout, 64..100: Wemb, pad 0)
// wlastT [256][320] (k<256: W_last[31+k], 256..286: W_last[k-256], pad 0)
// ---------------------------------------------------------------------------
__global__ __launch_bounds__(256) void pack_weights(
    const float* __restrict__ Wq, const float* __restrict__ Wk,
    const float* __restrict__ Wv, const float* __restrict__ Wemb,
    const float* __restrict__ Wout, const float* __restrict__ Wlast,
    unsigned short* __restrict__ wkvT, unsigned short* __restrict__ wqT,
    unsigned short* __restrict__ wmsgT, unsigned short* __restrict__ wlastT)
{
  int t = blockIdx.x * 256 + threadIdx.x;   // grid = 512 blocks -> t < 131072
  {
    int n = t >> 8, k = t & 255;
    wkvT[n * 256 + kswz(k, n)] =
        f2b((n < 256) ? Wk[k * 256 + n] : Wv[k * 256 + (n - 256)]);
  }
  if (t < 65536) {
    int n = t >> 8, k = t & 255;
    wqT[n * 256 + kswz(k, n)] = f2b(Wq[k * 256 + n]);
  }
  if (t < 32768) {
    int n = t >> 7, k = t & 127;
    float v = 0.f;
    if (k < 64)       v = Wout[k * 256 + n];
    else if (k < 101) v = Wemb[(k - 64) * 256 + n];
    wmsgT[n * 128 + kswz(k, n)] = f2b(v);
  }
  if (t < 256 * KL) {
    int n = t / KL, k = t % KL;
    float v = 0.f;
    if (k < 256)      v = Wlast[(31 + k) * 256 + n];
    else if (k < 287) v = Wlast[(k - 256) * 256 + n];
    wlastT[n * KL + kswz(k, n)] = f2b(v);
  }
}

// A2 [MB_PAD][128]: cols 0..63 = 0 (att slot), 64..100 = bf16(fbonds), rest 0
__global__ __launch_bounds__(256) void pack_bonds(
    const float* __restrict__ fbonds, unsigned short* __restrict__ A2)
{
  int t = blockIdx.x * 256 + threadIdx.x;
  int r = t >> 7, c = t & 127;
  float v = 0.f;
  if (c >= 64 && c < 101 && r < N_BONDS) v = fbonds[r * 37 + (c - 64)];
  A2[t] = f2b(v);
}

// ---------------------------------------------------------------------------
// m97-style 128x128 bf16 GEMM. A [*,K] row-major bf16 (linear),
// BT [N,K] row-major bf16 PRE-SWIZZLED (see kswz).
// Grid transposed (r6): blockIdx.x = N-tile, blockIdx.y = M-tile (neutral
// measured, kept: A row-panel re-reads are temporally adjacent).
// EP: 1 +bias Xf[col] leaky -> bf16;
//     3 +bias Xf[col] leaky, row<Mreal guard -> FLOAT out
//     4 kv epilogue: col<256 -> fp8 @ row*768+col; else bf16 @ row*768+256+(col-256)*2
// ---------------------------------------------------------------------------
template<int EP>
__global__ __launch_bounds__(256) void gemm_bt(
    const unsigned short* __restrict__ A,
    const unsigned short* __restrict__ BT,
    unsigned short* __restrict__ C0,
    float* __restrict__ Fout,
    const float* __restrict__ Xf,
    int K, int N, int Mreal)
{
  __shared__ __align__(16) unsigned short As[128 * 64];
  __shared__ __align__(16) unsigned short Bs[128 * 64];
  const int tid  = threadIdx.x;
  const int wave = tid >> 6, lane = tid & 63;
  const int wr = wave >> 1, wc = wave & 1;
  const int lhi = lane >> 4, llo = lane & 15;
  const int mBase = blockIdx.y * 128;   // transposed grid
  const int nBase = blockIdx.x * 128;
  const int crow = tid >> 3, ccol = tid & 7;   // per-lane staging coords

  f32x4 acc[4][4];
  #pragma unroll
  for (int i = 0; i < 4; ++i)
    #pragma unroll
    for (int j = 0; j < 4; ++j)
      acc[i][j] = f32x4{0.f, 0.f, 0.f, 0.f};

  for (int k0 = 0; k0 < K; k0 += 64) {
    __syncthreads();
    #pragma unroll
    for (int r = 0; r < 4; ++r) {
      const unsigned short* ga =
          A + (size_t)(mBase + r * 32 + crow) * K + (k0 + ccol * 8);
      __builtin_amdgcn_global_load_lds(
          (const __attribute__((address_space(1))) void*)ga,
          (__attribute__((address_space(3))) void*)(As + r * 2048 + wave * 512), 16, 0, 0);
      const unsigned short* gb =
          BT + (size_t)(nBase + r * 32 + crow) * K + (k0 + ccol * 8);
      __builtin_amdgcn_global_load_lds(
          (const __attribute__((address_space(1))) void*)gb,
          (__attribute__((address_space(3))) void*)(Bs + r * 2048 + wave * 512), 16, 0, 0);
    }
    __syncthreads();
    #pragma unroll
    for (int ks = 0; ks < 2; ++ks) {
      bf16x8 af[4], bfv[4];
      #pragma unroll
      for (int i = 0; i < 4; ++i)
        af[i] = *reinterpret_cast<const bf16x8*>(&As[(wr * 64 + i * 16 + llo) * 64 + ks * 32 + lhi * 8]);
      #pragma unroll
      for (int j = 0; j < 4; ++j)
        bfv[j] = *reinterpret_cast<const bf16x8*>(
            &Bs[(wc * 64 + j * 16 + llo) * 64 + ((ks * 32 + lhi * 8) ^ ((llo & 7) << 3))]);
      #pragma unroll
      for (int i = 0; i < 4; ++i)
        #pragma unroll
        for (int j = 0; j < 4; ++j)
          acc[i][j] = __builtin_amdgcn_mfma_f32_16x16x32_bf16(af[i], bfv[j], acc[i][j], 0, 0, 0);
    }
  }

  #pragma unroll
  for (int i = 0; i < 4; ++i) {
    #pragma unroll
    for (int j = 0; j < 4; ++j) {
      const int col = nBase + wc * 64 + j * 16 + llo;
      #pragma unroll
      for (int r = 0; r < 4; ++r) {
        const int row = mBase + wr * 64 + i * 16 + lhi * 4 + r;
        const float v = acc[i][j][r];
        if (EP == 0) {
          C0[(size_t)row * N + col] = f2b(v);
        } else if (EP == 1) {
          C0[(size_t)row * N + col] = f2b(lrelu(v + Xf[col]));
        } else if (EP == 3) {
          if (row < Mreal) Fout[(size_t)row * N + col] = lrelu(v + Xf[col]);
        } else {  // EP == 4: mixed fp8-K / bf16-V strided kv row
          unsigned char* kvb = (unsigned char*)C0;
          if (nBase < 256) {
            kvb[(size_t)row * KVSTRIDE + col] = f2e4m3(v);
          } else {
            *(unsigned short*)(kvb + (size_t)row * KVSTRIDE + 256 +
                               (size_t)(col - 256) * 2) = f2b(v);
          }
        }
      }
    }
  }
}

// ---------------------------------------------------------------------------
// Fused q-GEMM + attention. One block = 64 bonds, 512 thr:
//   phase 1: q[64][256] = msg_tile @ WqT via MFMA, result kept in LDS.
//   phase 2: 8 waves x 8 bonds, processed as 4 PAIRS. Each pair issues BOTH
//     bonds' 24 gather loads before either bond's compute -> 2x loads in
//     flight per wave (round 7's serial unroll kept only 12: VGPR_Count 40
//     proved the scheduler sank loads to uses). ALL per-neighbor state is
//     NAMED SCALARS (no arrays anywhere) -> nothing for the register
//     allocator to demote as an aggregate (the r3/r4 scratch mechanism).
// SCRATCH LESSON (r3/r4): conditional writes to loop-carried ARRAYS defeat
// SROA -> aggregate demotion -> scratch (WRITE_SIZE 25 -> 580-990 MB).
// Named scalars are immune; watch WRITE_SIZE stays ~25 MB.
// ---------------------------------------------------------------------------
#ifdef HW_PKFP8
#define QKDOT(p_, kd_) do {                                                    \
    const f32x2 lo_ = __builtin_amdgcn_cvt_pk_f32_fp8((int)(kd_), false);      \
    const f32x2 hi_ = __builtin_amdgcn_cvt_pk_f32_fp8((int)(kd_), true);       \
    p_ = q0 * lo_.x + q1 * lo_.y + q2 * hi_.x + q3 * hi_.y;                    \
  } while (0)
#else
#define QKDOT(p_, kd_) do {                                                    \
    p_ = q0 * DEC0(kd_) + q1 * DEC1(kd_) + q2 * DEC2(kd_) + q3 * DEC3(kd_);    \
  } while (0)
#endif

// One neighbor's gather state, fully named (bn/bp uniform -> SGPR; kd/vu VGPR)
#define NLOAD(P, N_)                                                           \
    const int bn##P##N_ = __builtin_amdgcn_readfirstlane(                      \
        bgraph[(size_t)uw##P * NEI + N_]);                                     \
    const unsigned char* bp##P##N_ =                                           \
        kv + (size_t)(unsigned)bn##P##N_ * KVSTRIDE;                           \
    const unsigned kd##P##N_ =                                                 \
        *reinterpret_cast<const unsigned*>(bp##P##N_ + lane * 4);              \
    const ushort4 vu##P##N_ =                                                  \
        *reinterpret_cast<const ushort4*>(bp##P##N_ + 256 + lane * 8);

#define GATHER(P, BL)                                                          \
    const int bl##P = (BL);                                                    \
    const int uw##P = __builtin_amdgcn_readfirstlane(mBase + bl##P);           \
    NLOAD(P, 0) NLOAD(P, 1) NLOAD(P, 2) NLOAD(P, 3) NLOAD(P, 4) NLOAD(P, 5)

#define NSCORE(P, N_)                                                          \
    float sc##P##N_;                                                           \
    {                                                                          \
      float p_;                                                                \
      QKDOT(p_, kd##P##N_);                                                    \
      p_ += __shfl_xor(p_, 1); p_ += __shfl_xor(p_, 2);                        \
      p_ += __shfl_xor(p_, 4); p_ += __shfl_xor(p_, 8);                        \
      sc##P##N_ = p_ * SCL + (bn##P##N_ != 0 ? 0.f : -1e7f);                   \
    }

#define NPV(P, N_)                                                             \
    {                                                                          \
      const float e_ = exp2f(sc##P##N_ - m_);                                  \
      s_ += e_;                                                                \
      o0_ += e_ * b2f(vu##P##N_.x); o1_ += e_ * b2f(vu##P##N_.y);              \
      o2_ += e_ * b2f(vu##P##N_.z); o3_ += e_ * b2f(vu##P##N_.w);              \
    }

#define COMPUTE(P)                                                             \
    {                                                                          \
      const ushort4 qu_ = *reinterpret_cast<const ushort4*>(                   \
          &smem[bl##P * QSTR + lane * 4]);                                     \
      const float q0 = b2f(qu_.x), q1 = b2f(qu_.y);                            \
      const float q2 = b2f(qu_.z), q3 = b2f(qu_.w);                            \
      NSCORE(P, 0) NSCORE(P, 1) NSCORE(P, 2)                                   \
      NSCORE(P, 3) NSCORE(P, 4) NSCORE(P, 5)                                   \
      const float m_ =                                                         \
          fmaxf(fmaxf(fmaxf(sc##P##0, sc##P##1), fmaxf(sc##P##2, sc##P##3)),   \
                fmaxf(sc##P##4, sc##P##5));                                    \
      float s_ = 0.f, o0_ = 0.f, o1_ = 0.f, o2_ = 0.f, o3_ = 0.f;              \
      NPV(P, 0) NPV(P, 1) NPV(P, 2) NPV(P, 3) NPV(P, 4) NPV(P, 5)              \
      const float inv_ = 0.25f * __builtin_amdgcn_rcpf(s_);                    \
      o0_ *= inv_; o1_ *= inv_; o2_ *= inv_; o3_ *= inv_;                      \
      o0_ += __shfl_xor(o0_, 16); o0_ += __shfl_xor(o0_, 32);                  \
      o1_ += __shfl_xor(o1_, 16); o1_ += __shfl_xor(o1_, 32);                  \
      o2_ += __shfl_xor(o2_, 16); o2_ += __shfl_xor(o2_, 32);                  \
      o3_ += __shfl_xor(o3_, 16); o3_ += __shfl_xor(o3_, 32);                  \
      if (lane < 16) {                                                         \
        ushort4 ov_;                                                           \
        ov_.x = f2b(o0_); ov_.y = f2b(o1_);                                    \
        ov_.z = f2b(o2_); ov_.w = f2b(o3_);                                    \
        *reinterpret_cast<ushort4*>(                                           \
            A2 + (size_t)(mBase + bl##P) * 128 + lane * 4) = ov_;              \
      }                                                                        \
    }

__global__ __launch_bounds__(512, 6) void fused_qattn(
    const unsigned short* __restrict__ msg,
    const unsigned short* __restrict__ wqT,
    const unsigned char* __restrict__ kv,
    const int* __restrict__ bgraph,
    unsigned short* __restrict__ A2)
{
  // phase 1: As [64][64] @0 (4096 sh), Bs [256][64] @4096 (16384 sh)
  // phase 2: q [64][QSTR] @0 (16640 sh).  union = 20480 shorts = 40 KB
  __shared__ __align__(16) unsigned short smem[20480];
  const int tid  = threadIdx.x;
  const int wave = tid >> 6, lane = tid & 63;
  const int wr = wave >> 2, wc = wave & 3;     // 2x4 wave grid, 32x64 per wave
  const int lhi = lane >> 4, llo = lane & 15;
  const int mBase = blockIdx.x * 64;
  const int crow = tid >> 3, ccol = tid & 7;   // staging coords (512 thr)

  // ---- phase 1: q = msg_tile @ WqT (K=256, N=256) ----
  f32x4 acc[2][4];
  #pragma unroll
  for (int i = 0; i < 2; ++i)
    #pragma unroll
    for (int j = 0; j < 4; ++j)
      acc[i][j] = f32x4{0.f, 0.f, 0.f, 0.f};

  for (int k0 = 0; k0 < 256; k0 += 64) {
    __syncthreads();
    {  // A: 64 rows in one round (512 lanes x 16 B = 8 KB), NT policy
      const unsigned short* ga =
          msg + (size_t)(mBase + crow) * 256 + (k0 + ccol * 8);
      __builtin_amdgcn_global_load_lds(
          (const __attribute__((address_space(1))) void*)ga,
          (__attribute__((address_space(3))) void*)(smem + wave * 512), 16, 0, AUX_NT);
    }
    #pragma unroll
    for (int r = 0; r < 4; ++r) {            // B^T: 256 rows, 4 rounds (cached)
      const unsigned short* gb =
          wqT + (size_t)(r * 64 + crow) * 256 + (k0 + ccol * 8);
      __builtin_amdgcn_global_load_lds(
          (const __attribute__((address_space(1))) void*)gb,
          (__attribute__((address_space(3))) void*)(smem + 4096 + r * 4096 + wave * 512),
          16, 0, 0);
    }
    __syncthreads();
    #pragma unroll
    for (int ks = 0; ks < 2; ++ks) {
      bf16x8 af[2], bfv[4];
      #pragma unroll
      for (int i = 0; i < 2; ++i)
        af[i] = *reinterpret_cast<const bf16x8*>(
            &smem[(wr * 32 + i * 16 + llo) * 64 + ks * 32 + lhi * 8]);
      #pragma unroll
      for (int j = 0; j < 4; ++j)
        bfv[j] = *reinterpret_cast<const bf16x8*>(
            &smem[4096 + (wc * 64 + j * 16 + llo) * 64 +
                  ((ks * 32 + lhi * 8) ^ ((llo & 7) << 3))]);
      #pragma unroll
      for (int i = 0; i < 2; ++i)
        #pragma unroll
        for (int j = 0; j < 4; ++j)
          acc[i][j] = __builtin_amdgcn_mfma_f32_16x16x32_bf16(af[i], bfv[j], acc[i][j], 0, 0, 0);
    }
  }
  __syncthreads();   // all waves done reading As/Bs before overwrite with q

  #pragma unroll
  for (int i = 0; i < 2; ++i) {
    #pragma unroll
    for (int j = 0; j < 4; ++j) {
      const int col = wc * 64 + j * 16 + llo;
      #pragma unroll
      for (int r = 0; r < 4; ++r) {
        const int row = wr * 32 + i * 16 + lhi * 4 + r;
        smem[row * QSTR + col] = f2b(acc[i][j][r]);
      }
    }
  }
  __syncthreads();

  // ---- phase 2: attention, 4 pairs of bonds, 2-deep gather pipeline ----
  const float SCL = 0.125f * 1.44269504089f;   // (1/sqrt(KD)) * log2(e)
  const int b0 = wave * 8;
  const int nv = N_BONDS - (mBase + b0);
  if (nv >= 8) {
    // fast path: all 8 bonds valid (every wave in blocks 0..3124; N_BONDS =
    // 3125*64 exactly). Each pair: 24 loads issued, then 2 computes.
    { GATHER(A, b0 + 0) GATHER(B, b0 + 1) COMPUTE(A) COMPUTE(B) }
    { GATHER(A, b0 + 2) GATHER(B, b0 + 3) COMPUTE(A) COMPUTE(B) }
    { GATHER(A, b0 + 4) GATHER(B, b0 + 5) COMPUTE(A) COMPUTE(B) }
    { GATHER(A, b0 + 6) GATHER(B, b0 + 7) COMPUTE(A) COMPUTE(B) }
  } else if (nv > 0) {
    // safety net (unreachable for N_BONDS = 3125*64, kept for robustness)
    #pragma unroll 1
    for (int t2 = 0; t2 < nv; ++t2) { GATHER(A, b0 + t2) COMPUTE(A) }
  }
}

// One wave per atom: nei_sum (fp32 accum) -> apad [MA_PAD][320]
// = [nei_sum(256) | bf16(fatoms)(31) | zeros]
__global__ __launch_bounds__(256) void atom_gather(
    const unsigned short* __restrict__ msg,
    const int* __restrict__ agraph,
    const float* __restrict__ fatoms,
    unsigned short* __restrict__ apad)
{
  const int aid  = blockIdx.x * 4 + (threadIdx.x >> 6);
  const int lane = threadIdx.x & 63;
  if (aid >= N_ATOMS) return;
  float s0 = 0, s1 = 0, s2 = 0, s3 = 0;
  #pragma unroll
  for (int n = 0; n < NEI; ++n) {
    const int b = agraph[aid * NEI + n];
    const ushort4 u = *reinterpret_cast<const ushort4*>(msg + (size_t)b * 256 + lane * 4);
    s0 += b2f(u.x); s1 += b2f(u.y); s2 += b2f(u.z); s3 += b2f(u.w);
  }
  ushort4 ov; ov.x = f2b(s0); ov.y = f2b(s1); ov.z = f2b(s2); ov.w = f2b(s3);
  *reinterpret_cast<ushort4*>(apad + (size_t)aid * KL + lane * 4) = ov;
  apad[(size_t)aid * KL + 256 + lane] =
      (lane < 31) ? f2b(fatoms[(size_t)aid * 31 + lane]) : (unsigned short)0;
}

// Diagnostic: zero output, out[0] = code (distinguishable absmax)
__global__ __launch_bounds__(256) void diag_out(float* out, int n, float code) {
  int t = blockIdx.x * 256 + threadIdx.x;
  if (t < n) out[t] = (t == 0) ? code : 0.f;
}

extern "C" void kernel_launch(void* const* d_in, const int* in_sizes, int n_in,
                              void* d_out, int out_size, void* d_ws, size_t ws_size,
                              hipStream_t stream) {
  const float* fatoms = (const float*)d_in[0];
  const float* fbonds = (const float*)d_in[1];
  const int* agraph   = (const int*)d_in[2];
  const int* bgraph   = (const int*)d_in[3];
  // d_in[4] lig_scope: unused by the reference computation
  const float* Wemb   = (const float*)d_in[5];
  const float* bemb   = (const float*)d_in[6];
  const float* Wq     = (const float*)d_in[7];
  const float* Wk     = (const float*)d_in[8];
  const float* Wv     = (const float*)d_in[9];
  const float* Wout   = (const float*)d_in[10];
  const float* Wlast  = (const float*)d_in[11];
  const float* blast  = (const float*)d_in[12];
  float* out          = (float*)d_out;

  char* ws = (char*)d_ws;
  size_t off = 0;
  auto alloc = [&](size_t bytes) {
    char* p = ws + off; off += (bytes + 511) & ~(size_t)511; return p;
  };
  unsigned short* msg    = (unsigned short*)alloc((size_t)MB_PAD * 256 * 2);
  unsigned char*  kv     = (unsigned char*)alloc((size_t)MB_PAD * KVSTRIDE); // atom-A alias
  unsigned short* A2     = (unsigned short*)alloc((size_t)MB_PAD * 128 * 2);
  unsigned short* wkvT   = (unsigned short*)alloc((size_t)512 * 256 * 2);
  unsigned short* wqT    = (unsigned short*)alloc((size_t)256 * 256 * 2);
  unsigned short* wmsgT  = (unsigned short*)alloc((size_t)256 * 128 * 2);
  unsigned short* wlastT = (unsigned short*)alloc((size_t)256 * KL * 2);
  unsigned short* apad   = (unsigned short*)kv;  // kv dead after loop (64.1 <= 153.6 MB)

  if (off > ws_size) {   // workspace too small: diagnostic
    diag_out<<<dim3((out_size + 255) / 256), dim3(256), 0, stream>>>(
        out, out_size, 10000.f + (float)(ws_size >> 20));
    return;
  }

  pack_weights<<<dim3(512), dim3(256), 0, stream>>>(
      Wq, Wk, Wv, Wemb, Wout, Wlast, wkvT, wqT, wmsgT, wlastT);
  pack_bonds<<<dim3(MB_PAD * 128 / 256), dim3(256), 0, stream>>>(fbonds, A2);

  // initial message: att cols of A2 are zero -> msg = leaky(fbonds@Wemb + b)
  // (grid transposed: x = N-tiles, y = M-tiles)
  gemm_bt<1><<<dim3(2, MT_B), dim3(256), 0, stream>>>(
      A2, wmsgT, msg, (float*)nullptr, bemb, 128, 256, MB_PAD);

  for (int it = 0; it < ITERS - 1; ++it) {
    // fused KV GEMM: [K-fp8 | V-bf16] strided rows (kv L3-hot for fused attn)
    gemm_bt<4><<<dim3(4, MT_B), dim3(256), 0, stream>>>(
        msg, wkvT, (unsigned short*)kv, (float*)nullptr, (const float*)nullptr,
        256, 512, MB_PAD);
    // q computed per-tile in LDS + attention; q never touches HBM
    fused_qattn<<<dim3(MT_Q), dim3(512), 0, stream>>>(msg, wqT, kv, bgraph, A2);
    // msg = leaky([att|fbonds] @ [Wout;Wemb] + b_emb)
    gemm_bt<1><<<dim3(2, MT_B), dim3(256), 0, stream>>>(
        A2, wmsgT, msg, (float*)nullptr, bemb, 128, 256, MB_PAD);
  }

  atom_gather<<<dim3(N_ATOMS / 4), dim3(256), 0, stream>>>(msg, agraph, fatoms, apad);
  gemm_bt<3><<<dim3(2, MT_A), dim3(256), 0, stream>>>(
      apad, wlastT, (unsigned short*)nullptr, out, blast, KL, 256, N_ATOMS);
}